// Round 16
// baseline (331.103 us; speedup 1.0000x reference)
//
#include <hip/hip_runtime.h>

// SemanticCaps dynamic routing, fp32. B=128, J=10, K=1152, M=16, I=8.
// R21: SELF-PROFILING round. Production pipeline byte-identical to R20
// (128.87 µs champion: dual-pipe Ws + packed-fp32 u-compute). Appended:
// diag_kernel = exact MODE-1 iter body with the k-loop repeated 16x
// (staging once; sp2 writes rotate over 4 slices; earr parity continuous
// across reps). At ~170 µs it surfaces ABOVE the 41 µs poison fills in
// the top-5 and yields the first counter row ever seen for the iter
// structure (VALUBusy / Occupancy / FETCH / LDS-conflict / VGPR).
// Corrected floor model: ~3.5 µs/pass VALU (prior 13.8 forgot 4 SIMD/CU);
// measured ~11 µs kernel-only -> 3x gap, cause unknown -> buy counters.
// Pre-committed: VALUBusy>=55 -> cut VALU ops; <=35 & occ~30 -> KT=4
// grid-576 TLP; conflicts>1e6 -> pad xt2; FETCH>>30MB -> Ws residency.
// b-logit algebra: b after t iters = u.(v0+..+v_{t-1}) (b starts at 0).
//
// ws (floats): sp[2621440] v0T[20480] vsumT[20480] sp2[4*2621440]

#define B_ 128
#define J_ 10
#define K_ 1152
#define M_ 16
#define I_ 8
#define KT 9
#define NKT (K_ / KT)        // 128 k-tiles
#define RW (K_ * I_)         // 9216 floats per x batch-row
#define SVEC (J_ * B_ * M_)  // 20480 floats per fold-slice of sp
#define XT4 (KT * I_ / 4)    // 18 float4 per b-row of the x tile
#define WH (M_ / 2 * I_)     // 64 floats: LDS half (m=8..15) per (j,k)
#define WH4 (WH / 4)         // 16 float4

typedef float v2f __attribute__((ext_vector_type(2)));

// ---------- routing pass (production; byte-identical to R20) -----------------
template <int MODE>
__global__ __launch_bounds__(640)
void iter_kernel(const float* __restrict__ x, const float* __restrict__ Ws,
                 const float* __restrict__ vinT, float* __restrict__ sp) {
    __shared__ v2f   xt2[KT * 4 * 64];
    __shared__ float earr[2][J_ * 64];
    __shared__ float wsh[J_ * KT * WH];
    const int t  = threadIdx.x;
    const int bl = t & 63;
    const int j  = __builtin_amdgcn_readfirstlane(t >> 6);
    const int kt = blockIdx.x, bg = blockIdx.y;
    const int b  = bg * 64 + bl;

    {
        const float4* x4 = (const float4*)x;
        for (int idx = t; idx < 64 * XT4; idx += 640) {
            const int bb = idx / XT4, q = idx % XT4;
            const float4 w = x4[(size_t)(bg * 64 + bb) * (RW / 4) + kt * XT4 + q];
            xt2[(2 * q + 0) * 64 + bb] = (v2f){w.x, w.y};
            xt2[(2 * q + 1) * 64 + bb] = (v2f){w.z, w.w};
        }
    }
    {
        const float4* ws4 = (const float4*)Ws;
        float4* dst = (float4*)wsh;
        for (int idx = t; idx < J_ * KT * WH4; idx += 640) {
            const int jj = idx / (KT * WH4);
            const int r  = idx % (KT * WH4);
            const int kk = r / WH4, q = r % WH4;
            dst[idx] = ws4[((size_t)jj * K_ + (size_t)kt * KT + kk) * 32 + 16 + q];
        }
    }

    v2f s2[M_];
#pragma unroll
    for (int m = 0; m < M_; ++m) s2[m] = (v2f){0.f, 0.f};
    v2f vsp[M_];
    if (MODE == 1) {
        const float4* vp = (const float4*)(vinT + ((size_t)j * B_ + b) * M_);
#pragma unroll
        for (int q = 0; q < 4; ++q) {
            const float4 w = vp[q];
            vsp[4*q]   = (v2f){w.x, w.x};
            vsp[4*q+1] = (v2f){w.y, w.y};
            vsp[4*q+2] = (v2f){w.z, w.z};
            vsp[4*q+3] = (v2f){w.w, w.w};
        }
    }
    __syncthreads();

    const float* wb = Ws + ((size_t)j * K_ + (size_t)kt * KT) * (M_ * I_);

    for (int kk = 0; kk < KT; ++kk) {
        v2f xr2[4];
#pragma unroll
        for (int ip = 0; ip < 4; ++ip)
            xr2[ip] = xt2[(kk * 4 + ip) * 64 + bl];

        v2f uh[M_];
        const v2f* w2 = (const v2f*)(wb + (size_t)kk * (M_ * I_));
#pragma unroll
        for (int m = 0; m < 8; ++m) {
            v2f a = w2[m * 4 + 0] * xr2[0];
            a += w2[m * 4 + 1] * xr2[1];
            a += w2[m * 4 + 2] * xr2[2];
            a += w2[m * 4 + 3] * xr2[3];
            uh[m] = a;
        }
        const float4* wl = (const float4*)(wsh + (j * KT + kk) * WH);
#pragma unroll
        for (int m4 = 0; m4 < 8; ++m4) {
            const float4 a4 = wl[2 * m4];
            const float4 b4 = wl[2 * m4 + 1];
            v2f a = (v2f){a4.x, a4.y} * xr2[0];
            a += (v2f){a4.z, a4.w} * xr2[1];
            a += (v2f){b4.x, b4.y} * xr2[2];
            a += (v2f){b4.z, b4.w} * xr2[3];
            uh[8 + m4] = a;
        }

        if (MODE == 1) {
            v2f lg2 = (v2f){0.f, 0.f};
#pragma unroll
            for (int m = 0; m < M_; ++m) lg2 += uh[m] * vsp[m];
            const float lg = lg2.x + lg2.y;
            const float e = __expf(lg);
            earr[kk & 1][j * 64 + bl] = e;
            __syncthreads();
            float den = 0.f;
#pragma unroll
            for (int jj = 0; jj < J_; ++jj) den += earr[kk & 1][jj * 64 + bl];
            const float c = __fdividef(e, den);
            const v2f c2 = (v2f){c, c};
#pragma unroll
            for (int m = 0; m < M_; ++m) s2[m] += c2 * uh[m];
        } else {
#pragma unroll
            for (int m = 0; m < M_; ++m) s2[m] += uh[m];
        }
    }

    float4* o = (float4*)(sp + (((size_t)kt * J_ + j) * B_ + b) * M_);
#pragma unroll
    for (int q = 0; q < 4; ++q) {
        float4 w;
        w.x = s2[4*q].x   + s2[4*q].y;
        w.y = s2[4*q+1].x + s2[4*q+1].y;
        w.z = s2[4*q+2].x + s2[4*q+2].y;
        w.w = s2[4*q+3].x + s2[4*q+3].y;
        o[q] = w;
    }
}

// ---------- DIAGNOSTIC: MODE-1 body, k-loop x16, counters-visible ------------
__global__ __launch_bounds__(640)
void diag_kernel(const float* __restrict__ x, const float* __restrict__ Ws,
                 const float* __restrict__ vinT, float* __restrict__ sp2) {
    __shared__ v2f   xt2[KT * 4 * 64];
    __shared__ float earr[2][J_ * 64];
    __shared__ float wsh[J_ * KT * WH];
    const int t  = threadIdx.x;
    const int bl = t & 63;
    const int j  = __builtin_amdgcn_readfirstlane(t >> 6);
    const int kt = blockIdx.x, bg = blockIdx.y;
    const int b  = bg * 64 + bl;

    {
        const float4* x4 = (const float4*)x;
        for (int idx = t; idx < 64 * XT4; idx += 640) {
            const int bb = idx / XT4, q = idx % XT4;
            const float4 w = x4[(size_t)(bg * 64 + bb) * (RW / 4) + kt * XT4 + q];
            xt2[(2 * q + 0) * 64 + bb] = (v2f){w.x, w.y};
            xt2[(2 * q + 1) * 64 + bb] = (v2f){w.z, w.w};
        }
    }
    {
        const float4* ws4 = (const float4*)Ws;
        float4* dst = (float4*)wsh;
        for (int idx = t; idx < J_ * KT * WH4; idx += 640) {
            const int jj = idx / (KT * WH4);
            const int r  = idx % (KT * WH4);
            const int kk = r / WH4, q = r % WH4;
            dst[idx] = ws4[((size_t)jj * K_ + (size_t)kt * KT + kk) * 32 + 16 + q];
        }
    }

    v2f vsp[M_];
    {
        const float4* vp = (const float4*)(vinT + ((size_t)j * B_ + b) * M_);
#pragma unroll
        for (int q = 0; q < 4; ++q) {
            const float4 w = vp[q];
            vsp[4*q]   = (v2f){w.x, w.x};
            vsp[4*q+1] = (v2f){w.y, w.y};
            vsp[4*q+2] = (v2f){w.z, w.z};
            vsp[4*q+3] = (v2f){w.w, w.w};
        }
    }
    __syncthreads();

    const float* wb = Ws + ((size_t)j * K_ + (size_t)kt * KT) * (M_ * I_);

    for (int rep = 0; rep < 16; ++rep) {
        v2f s2[M_];
#pragma unroll
        for (int m = 0; m < M_; ++m) s2[m] = (v2f){0.f, 0.f};

        for (int kk = 0; kk < KT; ++kk) {
            const int par = (rep * KT + kk) & 1;   // continuous parity across reps
            v2f xr2[4];
#pragma unroll
            for (int ip = 0; ip < 4; ++ip)
                xr2[ip] = xt2[(kk * 4 + ip) * 64 + bl];

            v2f uh[M_];
            const v2f* w2 = (const v2f*)(wb + (size_t)kk * (M_ * I_));
#pragma unroll
            for (int m = 0; m < 8; ++m) {
                v2f a = w2[m * 4 + 0] * xr2[0];
                a += w2[m * 4 + 1] * xr2[1];
                a += w2[m * 4 + 2] * xr2[2];
                a += w2[m * 4 + 3] * xr2[3];
                uh[m] = a;
            }
            const float4* wl = (const float4*)(wsh + (j * KT + kk) * WH);
#pragma unroll
            for (int m4 = 0; m4 < 8; ++m4) {
                const float4 a4 = wl[2 * m4];
                const float4 b4 = wl[2 * m4 + 1];
                v2f a = (v2f){a4.x, a4.y} * xr2[0];
                a += (v2f){a4.z, a4.w} * xr2[1];
                a += (v2f){b4.x, b4.y} * xr2[2];
                a += (v2f){b4.z, b4.w} * xr2[3];
                uh[8 + m4] = a;
            }

            v2f lg2 = (v2f){0.f, 0.f};
#pragma unroll
            for (int m = 0; m < M_; ++m) lg2 += uh[m] * vsp[m];
            const float lg = lg2.x + lg2.y;
            const float e = __expf(lg);
            earr[par][j * 64 + bl] = e;
            __syncthreads();
            float den = 0.f;
#pragma unroll
            for (int jj = 0; jj < J_; ++jj) den += earr[par][jj * 64 + bl];
            const float c = __fdividef(e, den);
            const v2f c2 = (v2f){c, c};
#pragma unroll
            for (int m = 0; m < M_; ++m) s2[m] += c2 * uh[m];
        }

        // rotating live store (4 slices) — not removable across barriers
        float4* o = (float4*)(sp2 + (size_t)(rep & 3) * NKT * SVEC
                                  + (((size_t)kt * J_ + j) * B_ + b) * M_);
#pragma unroll
        for (int q = 0; q < 4; ++q) {
            float4 w;
            w.x = s2[4*q].x   + s2[4*q].y;
            w.y = s2[4*q+1].x + s2[4*q+1].y;
            w.z = s2[4*q+2].x + s2[4*q+2].y;
            w.w = s2[4*q+3].x + s2[4*q+3].y;
            o[q] = w;
        }
    }
}

// ---------- squash (unchanged) -----------------------------------------------
template <int SM>
__global__ __launch_bounds__(256)
void squash_kernel(const float* __restrict__ sp, const float* __restrict__ v0T,
                   float* __restrict__ dst) {
    __shared__ float red[4][64];
    const int t  = threadIdx.x;
    const int l  = t & 63;
    const int wv = t >> 6;
    const int g  = blockIdx.x * 64 + l;
    const int m = g & 15;
    const int b = (g >> 4) & 127;
    const int j = g >> 11;
    const float* p = sp + (size_t)((j * B_ + b) * M_ + m);
    float S = 0.f;
#pragma unroll 8
    for (int tt = wv * (NKT / 4); tt < (wv + 1) * (NKT / 4); ++tt)
        S += p[(size_t)tt * SVEC];
    red[wv][l] = S;
    __syncthreads();
    if (wv == 0) {
        S = red[0][l] + red[1][l] + red[2][l] + red[3][l];
        if (SM == 0) S *= 0.1f;
        float sq = S * S;
        sq += __shfl_xor(sq, 1, 64);
        sq += __shfl_xor(sq, 2, 64);
        sq += __shfl_xor(sq, 4, 64);
        sq += __shfl_xor(sq, 8, 64);
        const float n = sqrtf(sq);
        float v = S * (n / (1.f + sq));
        if (SM == 1) v += v0T[g];
        if (SM == 2) dst[((size_t)b * J_ + j) * M_ + m] = v;
        else         dst[g] = v;
    }
}

extern "C" void kernel_launch(void* const* d_in, const int* in_sizes, int n_in,
                              void* d_out, int out_size, void* d_ws, size_t ws_size,
                              hipStream_t stream) {
    const float* x  = (const float*)d_in[0];
    const float* Ws = (const float*)d_in[1];
    float* out = (float*)d_out;

    float* sp    = (float*)d_ws;                           // 2,621,440 floats
    float* v0T   = sp + (size_t)NKT * SVEC;                //    20,480
    float* vsumT = v0T + SVEC;                             //    20,480
    float* sp2   = vsumT + SVEC;                           // 4×2,621,440 scratch

    iter_kernel<0><<<dim3(NKT, 2), 640, 0, stream>>>(x, Ws, nullptr, sp);
    squash_kernel<0><<<320, 256, 0, stream>>>(sp, nullptr, v0T);

    iter_kernel<1><<<dim3(NKT, 2), 640, 0, stream>>>(x, Ws, v0T, sp);
    squash_kernel<1><<<320, 256, 0, stream>>>(sp, v0T, vsumT);

    iter_kernel<1><<<dim3(NKT, 2), 640, 0, stream>>>(x, Ws, vsumT, sp);
    squash_kernel<2><<<320, 256, 0, stream>>>(sp, nullptr, out);

    // DIAGNOSTIC (after out is final; scratch-only writes):
    diag_kernel<<<dim3(NKT, 2), 640, 0, stream>>>(x, Ws, vsumT, sp2);
}

// Round 17
// 109.859 us; speedup vs baseline: 3.0139x; 3.0139x over previous
//
#include <hip/hip_runtime.h>

// SemanticCaps dynamic routing, fp32. B=128, J=10, K=1152, M=16, I=8.
// R22: MFMA u-compute. R21 diag (first real counters): k-loop = 14.8 µs,
// VALUBusy 50%, occ 28%, conflicts negligible -> split VALU / LDS-pipe
// bound; 16 broadcast ds_read_b128 per wave/k (Ws) + 10x duplicated den
// reads are the waste. Fix: per (j,k,16b-subtile) ONE mfma_f32_16x16x32_bf16
// with K-slots = precision triple [Whi|Wlo|Whi|0]x[xhi|xhi|xlo|-] ->
// Whi·xhi+Wlo·xhi+Whi·xlo in fp32 accum (dropped Wlo·xlo ~2^-18; est.
// out-error ~1e-7 << 5.95e-5 threshold). Ws/x staged ONCE as bf16 hi/lo;
// A=1 b128, B=4 b128 per wave/k (was 16 b128 + 64 pk_fma). den deduped:
// wave0 computes, 2nd barrier, others read 4 b32 (was 10/lane dup).
// D layout (m89-verified): col=lane&15=b, row=(l>>4)*4+reg=m -> lane l
// owns b=l for the earr write; softmax = 2 shuffles/subtile.
// RISK (pre-committed): A/B fragment layout inferred (row=l&15,
// k=(l>>4)*8+0..8). If absmax fails -> layout swap next round.
// b-logit algebra: b after t iters = u.(v0+..+v_{t-1}) (b starts at 0).
//
// ws (floats): sp[128*10*128*16] v0T[20480] vsumT[20480]

#define B_ 128
#define J_ 10
#define K_ 1152
#define M_ 16
#define I_ 8
#define KT 9
#define NKT (K_ / KT)        // 128 k-tiles
#define RW (K_ * I_)         // 9216 floats per x batch-row
#define SVEC (J_ * B_ * M_)  // 20480 floats per fold-slice of sp
#define XT4 (KT * I_ / 4)    // 18 float4 per b-row of the x tile
#define WTOT (J_ * KT * M_ * I_)   // 11520 Ws elements per block
#define XTOT (KT * 64 * I_)        // 4608 x elements per block

typedef short bf16x8 __attribute__((ext_vector_type(8)));
typedef float f32x4  __attribute__((ext_vector_type(4)));

__device__ __forceinline__ ushort bf_hi(float f) {
    return (ushort)(__float_as_uint(f) >> 16);   // truncate; residual captured in lo
}
__device__ __forceinline__ float bf_f(ushort h) {
    return __uint_as_float((unsigned)h << 16);
}

// ---------- routing pass -----------------------------------------------------
// MODE 0: c == 1 (iteration 0; 0.1 folded into squash<0>); acc chains in MFMA C.
// MODE 1: c = softmax_j(u . vin); per-k D=A·B, softmax, acc += c*D.
// Wave = output capsule j (10 waves); lane: col=l&15 (b within subtile),
// g=l>>4 (K-slot group / m-row group). 4 subtiles cover the block's 64 b.
template <int MODE>
__global__ __launch_bounds__(640)
void iter_kernel(const float* __restrict__ x, const float* __restrict__ Ws,
                 const float* __restrict__ vinT, float* __restrict__ sp) {
    __shared__ __align__(16) ushort whi[WTOT];   // [(j*KT+kk)*128 + m*8 + i]
    __shared__ __align__(16) ushort wlo[WTOT];
    __shared__ __align__(16) ushort xhi[XTOT];   // [(kk*64 + b)*8 + i]
    __shared__ __align__(16) ushort xlo[XTOT];
    __shared__ __align__(16) ushort zpad[8];     // 16B zeros (A group-3 slots)
    __shared__ float earr[J_ * 64];
    __shared__ float denl[64];

    const int t   = threadIdx.x;
    const int l   = t & 63;
    const int j   = __builtin_amdgcn_readfirstlane(t >> 6);  // wave-uniform j
    const int kt  = blockIdx.x, bg = blockIdx.y;
    const int col = l & 15;
    const int g   = l >> 4;

    // ---- stage Ws tile -> bf16 hi/lo ---------------------------------------
    {
        const float4* ws4 = (const float4*)Ws;
        for (int idx = t; idx < WTOT / 4; idx += 640) {          // 2880 float4
            const int jj = idx / (KT * 32);
            const int r  = idx % (KT * 32);
            const int kk = r / 32, q = r % 32;
            const float4 w = ws4[((size_t)jj * K_ + (size_t)kt * KT + kk) * 32 + q];
            const int base = (jj * KT + kk) * 128 + q * 4;
            ushort4 hv, lv;
            hv.x = bf_hi(w.x); lv.x = bf_hi(w.x - bf_f(hv.x));
            hv.y = bf_hi(w.y); lv.y = bf_hi(w.y - bf_f(hv.y));
            hv.z = bf_hi(w.z); lv.z = bf_hi(w.z - bf_f(hv.z));
            hv.w = bf_hi(w.w); lv.w = bf_hi(w.w - bf_f(hv.w));
            *(ushort4*)(whi + base) = hv;
            *(ushort4*)(wlo + base) = lv;
        }
    }
    // ---- stage x tile -> bf16 hi/lo ----------------------------------------
    {
        const float4* x4 = (const float4*)x;     // row stride RW/4 = 2304
        for (int idx = t; idx < 64 * XT4; idx += 640) {          // 1152 float4
            const int bb = idx / XT4, q = idx % XT4;
            const float4 w = x4[(size_t)(bg * 64 + bb) * (RW / 4) + kt * XT4 + q];
            const int kk = q >> 1, i0 = (q & 1) * 4;
            const int base = (kk * 64 + bb) * 8 + i0;
            ushort4 hv, lv;
            hv.x = bf_hi(w.x); lv.x = bf_hi(w.x - bf_f(hv.x));
            hv.y = bf_hi(w.y); lv.y = bf_hi(w.y - bf_f(hv.y));
            hv.z = bf_hi(w.z); lv.z = bf_hi(w.z - bf_f(hv.z));
            hv.w = bf_hi(w.w); lv.w = bf_hi(w.w - bf_f(hv.w));
            *(ushort4*)(xhi + base) = hv;
            *(ushort4*)(xlo + base) = lv;
        }
    }
    if (t < 8) zpad[t] = 0;

    // ---- v in MFMA-D layout: vd[s][r] = v[j][bg*64+s*16+col][g*4+r] --------
    f32x4 vd[4];
    if (MODE == 1) {
#pragma unroll
        for (int s = 0; s < 4; ++s)
            vd[s] = *(const f32x4*)(vinT
                      + ((size_t)j * B_ + bg * 64 + s * 16 + col) * M_ + g * 4);
    }
    __syncthreads();   // tiles ready

    f32x4 acc[4];
#pragma unroll
    for (int s = 0; s < 4; ++s) acc[s] = (f32x4){0.f, 0.f, 0.f, 0.f};

    // A-operand source per lane group: g0/g2 -> Whi, g1 -> Wlo, g3 -> zeros.
    const ushort* asrc = (g == 1) ? wlo : ((g == 3) ? zpad : whi);
    const int     amul = (g == 3) ? 0 : 1;
    // B-operand source: slots g0/g1 -> xhi, g2 -> xlo (g3 arbitrary: A=0).
    const ushort* bsrc = (g >= 2) ? xlo : xhi;

    for (int kk = 0; kk < KT; ++kk) {
        const bf16x8 af =
            *(const bf16x8*)(asrc + amul * ((j * KT + kk) * 128 + col * 8));
        f32x4 dd[4];
#pragma unroll
        for (int s = 0; s < 4; ++s) {
            const bf16x8 bf =
                *(const bf16x8*)(bsrc + (kk * 64 + s * 16 + col) * 8);
            if (MODE == 0) {
                acc[s] = __builtin_amdgcn_mfma_f32_16x16x32_bf16(af, bf, acc[s], 0, 0, 0);
            } else {
                dd[s] = __builtin_amdgcn_mfma_f32_16x16x32_bf16(
                            af, bf, (f32x4){0.f, 0.f, 0.f, 0.f}, 0, 0, 0);
            }
        }

        if (MODE == 1) {
            float es[4];
#pragma unroll
            for (int s = 0; s < 4; ++s) {
                float p = dd[s][0] * vd[s][0] + dd[s][1] * vd[s][1]
                        + dd[s][2] * vd[s][2] + dd[s][3] * vd[s][3];
                p += __shfl_xor(p, 16, 64);
                p += __shfl_xor(p, 32, 64);   // sum the 4 m-row groups
                es[s] = __expf(p);            // logit[b = s*16+col], all lanes
            }
            // lane l owns b=l: s=g, col=l&15 -> branchless select
            const float e01 = (g & 1) ? es[1] : es[0];
            const float e23 = (g & 1) ? es[3] : es[2];
            earr[j * 64 + l] = (g & 2) ? e23 : e01;
            __syncthreads();                  // barrier 1: e complete
            if (j == 0) {                     // dedup: wave 0 computes den[b]
                float den = 0.f;
#pragma unroll
                for (int jj = 0; jj < J_; ++jj) den += earr[jj * 64 + l];
                denl[l] = den;
            }
            __syncthreads();                  // barrier 2: den ready
#pragma unroll
            for (int s = 0; s < 4; ++s) {
                const float c = __fdividef(es[s], denl[s * 16 + col]);
#pragma unroll
                for (int r = 0; r < 4; ++r) acc[s][r] += c * dd[s][r];
            }
        }
    }

    // ---- write: lane holds (m = g*4+r, b = s*16+col) -> sp[kt][j][b][m] ----
    float* ob = sp + (((size_t)kt * J_ + j) * B_ + bg * 64) * M_;
#pragma unroll
    for (int s = 0; s < 4; ++s)
        *(f32x4*)(ob + (s * 16 + col) * M_ + g * 4) = acc[s];
}

// ---------- squash: parallel fold of 128 tile-partials, emit v ---------------
// SM 0: v0T = squash(0.1*S)  SM 1: vsumT = v0T + squash(S)  SM 2: out = squash(S)
template <int SM>
__global__ __launch_bounds__(256)
void squash_kernel(const float* __restrict__ sp, const float* __restrict__ v0T,
                   float* __restrict__ dst) {
    __shared__ float red[4][64];
    const int t  = threadIdx.x;
    const int l  = t & 63;
    const int wv = t >> 6;
    const int g  = blockIdx.x * 64 + l;   // g = (j*128+b)*16+m
    const int m = g & 15;
    const int b = (g >> 4) & 127;
    const int j = g >> 11;
    const float* p = sp + (size_t)((j * B_ + b) * M_ + m);
    float S = 0.f;
#pragma unroll 8
    for (int tt = wv * (NKT / 4); tt < (wv + 1) * (NKT / 4); ++tt)
        S += p[(size_t)tt * SVEC];
    red[wv][l] = S;
    __syncthreads();
    if (wv == 0) {
        S = red[0][l] + red[1][l] + red[2][l] + red[3][l];
        if (SM == 0) S *= 0.1f;
        float sq = S * S;
        sq += __shfl_xor(sq, 1, 64);
        sq += __shfl_xor(sq, 2, 64);
        sq += __shfl_xor(sq, 4, 64);
        sq += __shfl_xor(sq, 8, 64);      // sum over m within 16-lane group
        const float n = sqrtf(sq);
        float v = S * (n / (1.f + sq));
        if (SM == 1) v += v0T[g];
        if (SM == 2) dst[((size_t)b * J_ + j) * M_ + m] = v;   // standard [b][j][m]
        else         dst[g] = v;                                // vT layout
    }
}

extern "C" void kernel_launch(void* const* d_in, const int* in_sizes, int n_in,
                              void* d_out, int out_size, void* d_ws, size_t ws_size,
                              hipStream_t stream) {
    const float* x  = (const float*)d_in[0];   // [128][1152][8]
    const float* Ws = (const float*)d_in[1];   // [10][1152][16][8]
    float* out = (float*)d_out;                // [128][10][16]

    float* sp    = (float*)d_ws;                           // 2,621,440 floats
    float* v0T   = sp + (size_t)NKT * SVEC;                //    20,480
    float* vsumT = v0T + SVEC;                             //    20,480

    iter_kernel<0><<<dim3(NKT, 2), 640, 0, stream>>>(x, Ws, nullptr, sp);
    squash_kernel<0><<<320, 256, 0, stream>>>(sp, nullptr, v0T);

    iter_kernel<1><<<dim3(NKT, 2), 640, 0, stream>>>(x, Ws, v0T, sp);
    squash_kernel<1><<<320, 256, 0, stream>>>(sp, v0T, vsumT);

    iter_kernel<1><<<dim3(NKT, 2), 640, 0, stream>>>(x, Ws, vsumT, sp);
    squash_kernel<2><<<320, 256, 0, stream>>>(sp, nullptr, out);
}